// Round 10
// baseline (190.029 us; speedup 1.0000x reference)
//
#include <hip/hip_runtime.h>
#include <hip/hip_bf16.h>
#include <math.h>

typedef unsigned int u32;
typedef unsigned short ushort;

constexpr int N_NODES = 10000;
constexpr int N_EDGES = 320000;
constexpr float NEG_SLOPE = 0.2f;

typedef __attribute__((ext_vector_type(8))) _Float16 half8;  // 8 x fp16 (4 VGPRs)
typedef __attribute__((ext_vector_type(4))) float f32x4;
typedef __attribute__((ext_vector_type(16))) float f32x16;

// ---------------------------------------------------------------------------
// helpers
// ---------------------------------------------------------------------------
__device__ __forceinline__ float lrelu(float x) { return x > 0.f ? x : NEG_SLOPE * x; }
__device__ __forceinline__ float elu(float x)   { return x > 0.f ? x : (expf(x) - 1.f); }

__device__ __forceinline__ ushort f2h(float x) {
    _Float16 h = (_Float16)x;                 // RNE
    return __builtin_bit_cast(ushort, h);
}
__device__ __forceinline__ float h2f(ushort u) {
    return (float)__builtin_bit_cast(_Float16, u);
}

__device__ __forceinline__ void gload16(const void* g, void* l) {
    __builtin_amdgcn_global_load_lds(
        (__attribute__((address_space(1))) void*)g,
        (__attribute__((address_space(3))) void*)l, 16, 0, 0);
}

// ---------------------------------------------------------------------------
// K1: fused [chunked LDS histogram] + [W1/W2 transpose -> fp16] + [wl2/wr2]
//     + [h -> fp16]   (R3 form, unchanged)
// ---------------------------------------------------------------------------
constexpr int NCHUNK = 64;
constexpr int EPC    = N_EDGES / NCHUNK;                 // 5000 exactly
constexpr int NB_T1    = 64;                             // W1: 8x8 tiles of 64x64
constexpr int NB_T2    = 8;                              // W2: 8x1 tiles
constexpr int NB_WLR2  = 2;                              // 512 threads
constexpr int NB_PRE   = NCHUNK + NB_T1 + NB_T2 + NB_WLR2;
constexpr int NB_SPLIT = (N_NODES * 512 / 4) / 256;      // 5000 (1 float4/thread)

__global__ __launch_bounds__(256) void prep1_kernel(
                             const float4* __restrict__ h4,
                             ushort* __restrict__ xh,
                             const int* __restrict__ dst, int* __restrict__ ccnt,
                             int* __restrict__ rank,
                             const float* __restrict__ W1, ushort* __restrict__ w1t,
                             const float* __restrict__ W2, ushort* __restrict__ w2t,
                             const float* __restrict__ al2, const float* __restrict__ ar2,
                             float* __restrict__ wl2, float* __restrict__ wr2) {
    // one 40 KB buffer, aliased by hist (int[10000]) and transpose (float, pitch 65)
    __shared__ __align__(16) int shbuf[N_NODES];
    const int b = blockIdx.x;
    if (b < NCHUNK) {
        // ---- chunk histogram ----
        for (int i = threadIdx.x; i < N_NODES; i += 256) shbuf[i] = 0;
        __syncthreads();
        const int e0 = b * EPC;
#pragma unroll 4
        for (int i = threadIdx.x; i < EPC; i += 256) {
            const int e = e0 + i;
            rank[e] = atomicAdd(&shbuf[dst[e]], 1);   // LDS atomic
        }
        __syncthreads();
        for (int i = threadIdx.x; i < N_NODES; i += 256)
            ccnt[b * N_NODES + i] = shbuf[i];         // coalesced
    } else if (b < NCHUNK + NB_T1 + NB_T2) {
        float* smem = (float*)shbuf;                   // [64][65] pitch-65
        const int t0 = b - NCHUNK;
        const bool isW1 = t0 < NB_T1;
        const float* W = isW1 ? W1 : W2;
        ushort* wt = isW1 ? w1t : w2t;
        const int N  = isW1 ? 512 : 64;
        const int t  = isW1 ? t0 : (t0 - NB_T1);
        const int ti = isW1 ? (t & 7) : t;    // K-tile
        const int tj = isW1 ? (t >> 3) : 0;   // N-tile
        const int c  = threadIdx.x & 63;
        const int r0 = threadIdx.x >> 6;      // 0..3
#pragma unroll
        for (int p = 0; p < 16; p++) {
            const int r = p * 4 + r0;
            smem[r * 65 + c] = W[(size_t)(ti * 64 + r) * N + tj * 64 + c];
        }
        __syncthreads();
#pragma unroll
        for (int p = 0; p < 16; p++) {
            const int rr = p * 4 + r0;
            wt[(size_t)(tj * 64 + rr) * 512 + ti * 64 + c] = f2h(smem[c * 65 + rr]);
        }
    } else if (b < NB_PRE) {
        const int k = (b - NCHUNK - NB_T1 - NB_T2) * 256 + threadIdx.x;  // [0,512)
        float sl = 0.f, sr = 0.f;
#pragma unroll 8
        for (int d = 0; d < 64; d++) {
            const float w = W2[(size_t)k * 64 + d];
            sl += w * al2[d];
            sr += w * ar2[d];
        }
        wl2[k] = sl;
        wr2[k] = sr;
    } else {
        const int i = (b - NB_PRE) * 256 + threadIdx.x;
        const float4 v = h4[i];
        *(ushort4*)&xh[i * 4] = make_ushort4(f2h(v.x), f2h(v.y), f2h(v.z), f2h(v.w));
    }
}

// ---------------------------------------------------------------------------
// K2a: per-node exclusive scan across the 64 chunk counts (R3 form).
// ---------------------------------------------------------------------------
__global__ __launch_bounds__(256) void chunkscan_kernel(int* __restrict__ ccnt,
                                                        int* __restrict__ counts) {
    const int n = blockIdx.x * 256 + threadIdx.x;
    if (n >= N_NODES) return;
    int v[NCHUNK];
#pragma unroll
    for (int c = 0; c < NCHUNK; c++) v[c] = ccnt[c * N_NODES + n];
    int run = 0;
#pragma unroll
    for (int c = 0; c < NCHUNK; c++) {
        const int t = v[c];
        ccnt[c * N_NODES + n] = run;
        run += t;
    }
    counts[n] = run;
}

// ---------------------------------------------------------------------------
// K2b: scan counts -> offs. Single 256-thread block (R3 form).
// ---------------------------------------------------------------------------
__global__ void prep2_scan_kernel(const int* __restrict__ counts, int* __restrict__ offs) {
    __shared__ int wsum[4];
    const int tid = threadIdx.x;
    const int lane = tid & 63, wave = tid >> 6;
    const int base = tid * 40;
    int v[40];
    int s = 0;
#pragma unroll
    for (int i = 0; i < 40; i++) {
        v[i] = (base + i < N_NODES) ? counts[base + i] : 0;
        s += v[i];
    }
    int ps = s;
#pragma unroll
    for (int o = 1; o < 64; o <<= 1) {
        const int t = __shfl_up(ps, o);
        if (lane >= o) ps += t;
    }
    if (lane == 63) wsum[wave] = ps;
    __syncthreads();
    if (tid < 4) {
        int t = wsum[tid];
#pragma unroll
        for (int o = 1; o < 4; o <<= 1) {
            const int u = __shfl_up(t, o);
            if (tid >= o) t += u;
        }
        wsum[tid] = t;
    }
    __syncthreads();
    const int wbase = (wave > 0) ? wsum[wave - 1] : 0;
    int run = wbase + ps - s;
#pragma unroll
    for (int i = 0; i < 40; i++) {
        if (base + i < N_NODES) offs[base + i + 1] = run + v[i];
        run += v[i];
    }
    if (tid == 0) offs[0] = 0;
}

// ---------------------------------------------------------------------------
// K3: fused [GEMM1 + el/er epilogue] + [scatter]  (R3 form).
// ---------------------------------------------------------------------------
constexpr int NB_GEMM1 = ((N_NODES + 63) / 64) * 4;      // 628
constexpr int NB_SCAT  = (N_EDGES + 255) / 256;          // 1250

__global__ __launch_bounds__(256) void gemm1_scatter_kernel(
    const ushort* __restrict__ A, const ushort* __restrict__ B,
    ushort* __restrict__ Cout, int M,
    const float* __restrict__ attn_l, const float* __restrict__ attn_r,
    float* __restrict__ elp, float* __restrict__ erp,
    const int* __restrict__ src, const int* __restrict__ dst,
    const int* __restrict__ rank, const int* __restrict__ offs,
    const int* __restrict__ ccnt, int* __restrict__ srcs) {
    constexpr int BM = 64, BN = 128, BK = 64, K = 512, N = 512;

    if ((int)blockIdx.x >= NB_GEMM1) {
        const int i = ((int)blockIdx.x - NB_GEMM1) * 256 + threadIdx.x;
        if (i < N_EDGES) {
            const int c = i / EPC;                     // magic-div (constexpr)
            const int d = dst[i];
            srcs[offs[d] + ccnt[c * N_NODES + d] + rank[i]] = src[i];
        }
        return;
    }

    __shared__ __align__(16) ushort sA[2][BM * BK];   // 8 KB x2
    __shared__ __align__(16) ushort sB[2][BN * BK];   // 16 KB x2

    const int tid = threadIdx.x;
    const int wave = tid >> 6, lane = tid & 63;
    const int m0 = ((int)blockIdx.x >> 2) * BM, n0 = ((int)blockIdx.x & 3) * BN;
    const int wm = wave >> 1, wn = wave & 1;
    const int l31 = lane & 31, lh = lane >> 5;

    // --- staging maps: phys (row, slot) <- global (row, slot ^ (row&7)) ---
    size_t abyte[2]; int afb[2];
#pragma unroll
    for (int p = 0; p < 2; p++) {
        const int fb = tid * 16 + p * 4096;            // [0,8192)
        const int r = fb >> 7, s = (fb >> 4) & 7;
        int ar = m0 + r; if (ar > M - 1) ar = M - 1;
        abyte[p] = (size_t)ar * (K * 2) + (size_t)((s ^ (r & 7)) << 4);
        afb[p] = fb;
    }
    size_t bbyte[4]; int bfb[4];
#pragma unroll
    for (int p = 0; p < 4; p++) {
        const int fb = tid * 16 + p * 4096;            // [0,16384)
        const int r = fb >> 7, s = (fb >> 4) & 7;
        bbyte[p] = (size_t)(n0 + r) * (K * 2) + (size_t)((s ^ (r & 7)) << 4);
        bfb[p] = fb;
    }

    f32x16 acc[2] = {};

    const int rA = wm * 32 + l31;
    const u32 aoff = rA * 128, axr = rA & 7;
    u32 boff[2], bxr[2];
#pragma unroll
    for (int ni = 0; ni < 2; ni++) {
        const int rB = wn * 64 + ni * 32 + l31;
        boff[ni] = rB * 128; bxr[ni] = rB & 7;
    }

    // prologue: stage tile 0
#pragma unroll
    for (int p = 0; p < 2; p++) gload16((const char*)A + abyte[p], (char*)&sA[0][0] + afb[p]);
#pragma unroll
    for (int p = 0; p < 4; p++) gload16((const char*)B + bbyte[p], (char*)&sB[0][0] + bfb[p]);
    __syncthreads();

    int cur = 0;
    for (int k0 = 0; k0 < K; k0 += BK) {
        if (k0 + BK < K) {   // stage next tile while computing current
            const size_t kb = (size_t)(k0 + BK) * 2;
#pragma unroll
            for (int p = 0; p < 2; p++)
                gload16((const char*)A + abyte[p] + kb, (char*)&sA[cur ^ 1][0] + afb[p]);
#pragma unroll
            for (int p = 0; p < 4; p++)
                gload16((const char*)B + bbyte[p] + kb, (char*)&sB[cur ^ 1][0] + bfb[p]);
        }
        const char* pA = (const char*)&sA[cur][0];
        const char* pB = (const char*)&sB[cur][0];
#pragma unroll
        for (int ks = 0; ks < 4; ks++) {
            const u32 sl = ks * 2 + lh;
            const half8 ah = *(const half8*)(pA + aoff + ((sl ^ axr) << 4));
#pragma unroll
            for (int ni = 0; ni < 2; ni++) {
                const half8 bh = *(const half8*)(pB + boff[ni] + ((sl ^ bxr[ni]) << 4));
                acc[ni] = __builtin_amdgcn_mfma_f32_32x32x16_f16(ah, bh, acc[ni], 0, 0, 0);
            }
        }
        __syncthreads();   // drains prefetch vmcnt + protects buffer swap
        cur ^= 1;
    }

    // C layout (m74/m101, dtype-independent): col=lane&31,
    // row=(reg&3)+8*(reg>>2)+4*(lane>>5)
#pragma unroll
    for (int reg = 0; reg < 16; reg++) {
        const int grow = m0 + wm * 32 + (reg & 3) + 8 * (reg >> 2) + 4 * lh;
        if (grow < M) {
#pragma unroll
            for (int ni = 0; ni < 2; ni++) {
                const int gcol = n0 + wn * 64 + ni * 32 + l31;
                Cout[(size_t)grow * N + gcol] = f2h(acc[ni][reg]);
            }
        }
    }

    const int head = (n0 + wn * 64) >> 6;
    float alv[2], arv[2];
#pragma unroll
    for (int ni = 0; ni < 2; ni++) {
        alv[ni] = attn_l[head * 64 + ni * 32 + l31];
        arv[ni] = attn_r[head * 64 + ni * 32 + l31];
    }
#pragma unroll
    for (int reg = 0; reg < 16; reg++) {
        float pl = acc[0][reg] * alv[0] + acc[1][reg] * alv[1];
        float pr = acc[0][reg] * arv[0] + acc[1][reg] * arv[1];
#pragma unroll
        for (int o = 1; o < 32; o <<= 1) {
            pl += __shfl_xor(pl, o);
            pr += __shfl_xor(pr, o);
        }
        const int grow = m0 + wm * 32 + (reg & 3) + 8 * (reg >> 2) + 4 * lh;
        if (l31 == 0 && grow < M) {
            elp[grow * 8 + head] = pl;
            erp[grow * 8 + head] = pr;
        }
    }
}

// ---------------------------------------------------------------------------
// K5: layer-1 aggregation — R9's XCD-affine pair-slicing (L2-resident:
// FETCH 110 -> 15 MB measured) reshaped for VALU efficiency (R9 counters:
// VALUBusy 84% = instruction-bound). 8 edge-groups x 8 lanes; each lane
// covers 16 dims (32 B/edge: two dwordx4, 2nd folds to offset:16). Per
// 8-edge window: 1 shfl + 1 el load + 1 exp chain + 1 feat addr per lane
// (~30 wave-instr vs R9's ~42 for the same 8 edges x 128 dims). Clamping
// (min/cndmask) only in the tail window, not every window. Group partials
// combine via shfl_xor(8,16,32); logit partials via shfl_xor(1,2,4).
// ---------------------------------------------------------------------------
__global__ __launch_bounds__(256) void agg1_kernel(
    const ushort* __restrict__ feat, const float* __restrict__ el,
    const float* __restrict__ er, const int* __restrict__ offs,
    const int* __restrict__ srcs, ushort* __restrict__ xh,
    const float* __restrict__ wl2, const float* __restrict__ wr2,
    float* __restrict__ plp, float* __restrict__ prp) {
    const int tid = threadIdx.x;
    const int wave = tid >> 6, lane = tid & 63;
    const int pair = blockIdx.x & 3;                  // XCD-affine slice id
    const int node = (blockIdx.x >> 2) * 4 + wave;
    const int start = offs[node];
    const int deg = offs[node + 1] - start;
    const int grp = lane >> 3;                        // edge group 0..7
    const int lig = lane & 7;                         // lane in group
    const int d0  = pair * 128 + lig * 16;            // my 16 dims
    const int myh = pair * 2 + (lig >> 2);            // my head

    if (deg == 0) {
        if (lane < 8) {
            const ushort4 z = make_ushort4(0, 0, 0, 0);
#pragma unroll
            for (int q = 0; q < 4; q++)
                *(ushort4*)&xh[(size_t)node * 512 + d0 + q * 4] = z;
        }
        if (lane == 0) { plp[node * 4 + pair] = 0.f; prp[node * 4 + pair] = 0.f; }
        return;
    }

    const float er_my = er[node * 8 + myh];

    float acc[16];
#pragma unroll
    for (int i = 0; i < 16; i++) acc[i] = 0.f;
    float ws = 0.f;

    for (int base = 0; base < deg; base += 64) {
        const int has = min(64, deg - base);
        const int s = srcs[start + base + min(lane, has - 1)];
        int j = 0;
        // full 8-edge windows: no clamping needed
        for (; j + 8 <= has; j += 8) {
            const int se = __shfl(s, j + grp);
            const float le = el[se * 8 + myh];
            const ushort* fp = &feat[(size_t)se * 512 + d0];
            const half8 u0 = *(const half8*)fp;
            const half8 u1 = *(const half8*)(fp + 8);   // offset:16 fold
            const float w = __expf(lrelu(le + er_my));
#pragma unroll
            for (int i = 0; i < 8; i++) acc[i] += w * (float)u0[i];
#pragma unroll
            for (int i = 0; i < 8; i++) acc[8 + i] += w * (float)u1[i];
            ws += w;
        }
        // tail window (1..7 edges): clamped + masked
        if (j < has) {
            const int e = j + grp;
            const int se = __shfl(s, min(e, has - 1));
            const float le = el[se * 8 + myh];
            const ushort* fp = &feat[(size_t)se * 512 + d0];
            const half8 u0 = *(const half8*)fp;
            const half8 u1 = *(const half8*)(fp + 8);
            const float w = (e < has) ? __expf(lrelu(le + er_my)) : 0.f;
#pragma unroll
            for (int i = 0; i < 8; i++) acc[i] += w * (float)u0[i];
#pragma unroll
            for (int i = 0; i < 8; i++) acc[8 + i] += w * (float)u1[i];
            ws += w;
        }
    }

    // combine the 8 edge-groups (same dims at lanes l ^ {8,16,32})
#pragma unroll
    for (int i = 0; i < 16; i++) {
        acc[i] += __shfl_xor(acc[i], 8);
        acc[i] += __shfl_xor(acc[i], 16);
        acc[i] += __shfl_xor(acc[i], 32);
    }
    ws += __shfl_xor(ws, 8);
    ws += __shfl_xor(ws, 16);
    ws += __shfl_xor(ws, 32);

    const float inv = 1.f / ws;
    float o[16];
#pragma unroll
    for (int i = 0; i < 16; i++) o[i] = elu(acc[i] * inv);

    if (lane < 8) {
        ushort hh[16];
#pragma unroll
        for (int i = 0; i < 16; i++) hh[i] = f2h(o[i]);
#pragma unroll
        for (int q = 0; q < 4; q++)
            *(ushort4*)&xh[(size_t)node * 512 + d0 + q * 4] =
                make_ushort4(hh[q * 4], hh[q * 4 + 1], hh[q * 4 + 2], hh[q * 4 + 3]);
    }

    // per-pair partial layer-2 logits (reduce across the 8 dim-lanes)
    float pl = 0.f, pr = 0.f;
#pragma unroll
    for (int i = 0; i < 16; i++) {
        pl += o[i] * wl2[d0 + i];
        pr += o[i] * wr2[d0 + i];
    }
#pragma unroll
    for (int off = 4; off > 0; off >>= 1) {
        pl += __shfl_xor(pl, off);
        pr += __shfl_xor(pr, off);
    }
    if (lane == 0) { plp[node * 4 + pair] = pl; prp[node * 4 + pair] = pr; }
}

// ---------------------------------------------------------------------------
// GEMM2 (layer 2) + appended partial-logit sum blocks (el2/er2 = sum of the
// 4 pair partials; runs after agg1, before agg2).  (R9 form, unchanged)
// ---------------------------------------------------------------------------
constexpr int NB_G2  = (N_NODES + 31) / 32;              // 313
constexpr int NB_SUM = (N_NODES + 255) / 256;            // 40

__global__ __launch_bounds__(256) void gemm2_kernel(
    const ushort* __restrict__ A, const ushort* __restrict__ B,
    ushort* __restrict__ Cout, int M,
    const float* __restrict__ plp, const float* __restrict__ prp,
    float* __restrict__ el2, float* __restrict__ er2) {
    constexpr int BM = 32, BN = 64, BK = 64, K = 512, N = 64;

    if ((int)blockIdx.x >= NB_G2) {
        const int n = ((int)blockIdx.x - NB_G2) * 256 + threadIdx.x;
        if (n < N_NODES) {
            el2[n] = plp[n * 4] + plp[n * 4 + 1] + plp[n * 4 + 2] + plp[n * 4 + 3];
            er2[n] = prp[n * 4] + prp[n * 4 + 1] + prp[n * 4 + 2] + prp[n * 4 + 3];
        }
        return;
    }

    __shared__ __align__(16) ushort sA[2][BM * BK];   // 4 KB x2
    __shared__ __align__(16) ushort sB[2][BN * BK];   // 8 KB x2

    const int tid = threadIdx.x;
    const int wave = tid >> 6, lane = tid & 63;
    const int m0 = blockIdx.x * BM;
    const int wm = wave >> 1, wn = wave & 1;
    const int quad = lane >> 4, l15 = lane & 15;

    const int fa = tid * 16;                           // [0,4096)
    const int ra = fa >> 7, sa_ = (fa >> 4) & 7;
    int arow = m0 + ra; if (arow > M - 1) arow = M - 1;
    const size_t abyte = (size_t)arow * (K * 2) + (size_t)((sa_ ^ (ra & 7)) << 4);

    size_t bbyte[2]; int bfb[2];
#pragma unroll
    for (int p = 0; p < 2; p++) {
        const int fb = tid * 16 + p * 4096;            // [0,8192)
        const int r = fb >> 7, s = (fb >> 4) & 7;
        bbyte[p] = (size_t)r * (K * 2) + (size_t)((s ^ (r & 7)) << 4);
        bfb[p] = fb;
    }

    f32x4 acc[2] = {};
    const int rA = wm * 16 + l15;
    const u32 aoff = rA * 128, axr = rA & 7;
    u32 boff[2], bxr[2];
#pragma unroll
    for (int ni = 0; ni < 2; ni++) {
        const int rB = wn * 32 + ni * 16 + l15;
        boff[ni] = rB * 128; bxr[ni] = rB & 7;
    }

    gload16((const char*)A + abyte, (char*)&sA[0][0] + fa);
#pragma unroll
    for (int p = 0; p < 2; p++) gload16((const char*)B + bbyte[p], (char*)&sB[0][0] + bfb[p]);
    __syncthreads();

    int cur = 0;
    for (int k0 = 0; k0 < K; k0 += BK) {
        if (k0 + BK < K) {
            const size_t kb = (size_t)(k0 + BK) * 2;
            gload16((const char*)A + abyte + kb, (char*)&sA[cur ^ 1][0] + fa);
#pragma unroll
            for (int p = 0; p < 2; p++)
                gload16((const char*)B + bbyte[p] + kb, (char*)&sB[cur ^ 1][0] + bfb[p]);
        }
        const char* pA = (const char*)&sA[cur][0];
        const char* pB = (const char*)&sB[cur][0];
#pragma unroll
        for (int ks = 0; ks < 2; ks++) {
            const u32 sl = ks * 4 + quad;
            const half8 ah = *(const half8*)(pA + aoff + ((sl ^ axr) << 4));
#pragma unroll
            for (int ni = 0; ni < 2; ni++) {
                const half8 bh = *(const half8*)(pB + boff[ni] + ((sl ^ bxr[ni]) << 4));
                acc[ni] = __builtin_amdgcn_mfma_f32_16x16x32_f16(ah, bh, acc[ni], 0, 0, 0);
            }
        }
        __syncthreads();
        cur ^= 1;
    }

    // C layout 16x16 (m89): col=lane&15, row=(lane>>4)*4+reg
#pragma unroll
    for (int r = 0; r < 4; r++) {
        const int grow = m0 + wm * 16 + quad * 4 + r;
        if (grow < M) {
#pragma unroll
            for (int ni = 0; ni < 2; ni++) {
                const int gcol = wn * 32 + ni * 16 + l15;
                Cout[(size_t)grow * N + gcol] = f2h(acc[ni][r]);
            }
        }
    }
}

// ---------------------------------------------------------------------------
// Layer-2 aggregation (unchanged).
// ---------------------------------------------------------------------------
__global__ __launch_bounds__(256) void agg2_kernel(
    const ushort* __restrict__ feat, const float* __restrict__ el,
    const float* __restrict__ er, const int* __restrict__ offs,
    const int* __restrict__ srcs, float* __restrict__ out) {
    const int tid = threadIdx.x;
    const int wave = tid >> 6, lane = tid & 63;
    const int node = blockIdx.x * 4 + wave;
    const int start = offs[node];
    const int deg = offs[node + 1] - start;
    if (deg == 0) { out[(size_t)node * 64 + lane] = 0.f; return; }
    const float ern = er[node];

    float acc = 0.f, ws = 0.f;
    for (int base = 0; base < deg; base += 64) {
        const int has = min(64, deg - base);
        const int s = srcs[start + base + min(lane, has - 1)];
        const float w = __expf(lrelu(el[s] + ern));
        int j = 0;
        for (; j + 8 <= has; j += 8) {
            float aq[8]; int sq[8];
#pragma unroll
            for (int q = 0; q < 8; q++) { aq[q] = __shfl(w, j + q); sq[q] = __shfl(s, j + q); }
            ushort fq[8];
#pragma unroll
            for (int q = 0; q < 8; q++) fq[q] = feat[(size_t)sq[q] * 64 + lane];
#pragma unroll
            for (int q = 0; q < 8; q++) { acc += aq[q] * h2f(fq[q]); ws += aq[q]; }
        }
        for (; j < has; j++) {
            const float a = __shfl(w, j);
            const int sj = __shfl(s, j);
            acc += a * h2f(feat[(size_t)sj * 64 + lane]);
            ws += a;
        }
    }
    out[(size_t)node * 64 + lane] = acc / ws;
}

// ---------------------------------------------------------------------------
extern "C" void kernel_launch(void* const* d_in, const int* in_sizes, int n_in,
                              void* d_out, int out_size, void* d_ws, size_t ws_size,
                              hipStream_t stream) {
    const float* h   = (const float*)d_in[0];
    const int*   src = (const int*)d_in[1];
    const int*   dst = (const int*)d_in[2];
    const float* W1  = (const float*)d_in[3];
    const float* al1 = (const float*)d_in[4];
    const float* ar1 = (const float*)d_in[5];
    const float* W2  = (const float*)d_in[6];
    const float* al2 = (const float*)d_in[7];
    const float* ar2 = (const float*)d_in[8];
    float* out = (float*)d_out;

    // workspace carve (16B-aligned chunks)
    char* p = (char*)d_ws;
    ushort* feat1 = (ushort*)p; p += (size_t)N_NODES * 512 * 2;   // fp16, 10.24 MB
    ushort* feat2 = (ushort*)p; p += (size_t)N_NODES * 64 * 2;    // fp16
    float* el1   = (float*)p;  p += (size_t)N_NODES * 8 * 4;
    float* er1   = (float*)p;  p += (size_t)N_NODES * 8 * 4;
    float* el2   = (float*)p;  p += (size_t)N_NODES * 4;
    float* er2   = (float*)p;  p += (size_t)N_NODES * 4;
    ushort* xh   = (ushort*)p; p += (size_t)N_NODES * 512 * 2;    // h fp16 -> x1 fp16
    ushort* w1t  = (ushort*)p; p += (size_t)512 * 512 * 2;        // fp16
    ushort* w2t  = (ushort*)p; p += (size_t)64 * 512 * 2;         // fp16
    float* wl2   = (float*)p;  p += (size_t)512 * 4;
    float* wr2   = (float*)p;  p += (size_t)512 * 4;
    int* counts  = (int*)p;    p += (size_t)N_NODES * 4;          // node totals
    int* ccnt    = (int*)p;    p += (size_t)NCHUNK * N_NODES * 4; // 2.56 MB
    int* offs    = (int*)p;    p += (size_t)10004 * 4;
    int* rank    = (int*)p;    p += (size_t)N_EDGES * 4;
    int* srcs    = (int*)p;    p += (size_t)N_EDGES * 4;
    float* plp   = (float*)p;  p += (size_t)N_NODES * 4 * 4;      // pair partials
    float* prp   = (float*)p;  p += (size_t)N_NODES * 4 * 4;

    // 1: fused LDS-hist + W-transposes + wl2/wr2 + h->fp16  (no memset needed)
    prep1_kernel<<<NB_PRE + NB_SPLIT, 256, 0, stream>>>(
        (const float4*)h, xh, dst, ccnt, rank,
        W1, w1t, W2, w2t, al2, ar2, wl2, wr2);

    // 2a: per-node scan over chunks
    chunkscan_kernel<<<(N_NODES + 255) / 256, 256, 0, stream>>>(ccnt, counts);

    // 2b: scan counts -> offs (1 block)
    prep2_scan_kernel<<<1, 256, 0, stream>>>(counts, offs);

    // 3: fused GEMM1 (fp16, dbuf+swizzle, + el/er) + scatter
    gemm1_scatter_kernel<<<NB_GEMM1 + NB_SCAT, 256, 0, stream>>>(
        xh, w1t, feat1, N_NODES, al1, ar1, el1, er1,
        src, dst, rank, offs, ccnt, srcs);

    // 4: layer-1 aggregation (XCD-affine pair-slices, 8 groups x 16 dims/lane)
    agg1_kernel<<<N_NODES, 256, 0, stream>>>(
        feat1, el1, er1, offs, srcs, xh, wl2, wr2, plp, prp);

    // 5: layer-2 GEMM + partial-logit sum -> el2/er2
    gemm2_kernel<<<NB_G2 + NB_SUM, 256, 0, stream>>>(
        xh, w2t, feat2, N_NODES, plp, prp, el2, er2);

    // 6: layer-2 aggregation -> out
    agg2_kernel<<<N_NODES / 4, 256, 0, stream>>>(feat2, el2, er2, offs, srcs, out);
}

// Round 11
// 178.643 us; speedup vs baseline: 1.0637x; 1.0637x over previous
//
#include <hip/hip_runtime.h>
#include <hip/hip_bf16.h>
#include <math.h>

typedef unsigned int u32;
typedef unsigned short ushort;

constexpr int N_NODES = 10000;
constexpr int N_EDGES = 320000;
constexpr float NEG_SLOPE = 0.2f;

typedef __attribute__((ext_vector_type(8))) _Float16 half8;  // 8 x fp16 (4 VGPRs)
typedef __attribute__((ext_vector_type(4))) float f32x4;
typedef __attribute__((ext_vector_type(16))) float f32x16;

// ---------------------------------------------------------------------------
// helpers
// ---------------------------------------------------------------------------
__device__ __forceinline__ float lrelu(float x) { return x > 0.f ? x : NEG_SLOPE * x; }
__device__ __forceinline__ float elu(float x)   { return x > 0.f ? x : (expf(x) - 1.f); }

__device__ __forceinline__ ushort f2h(float x) {
    _Float16 h = (_Float16)x;                 // RNE
    return __builtin_bit_cast(ushort, h);
}
__device__ __forceinline__ float h2f(ushort u) {
    return (float)__builtin_bit_cast(_Float16, u);
}

__device__ __forceinline__ void gload16(const void* g, void* l) {
    __builtin_amdgcn_global_load_lds(
        (__attribute__((address_space(1))) void*)g,
        (__attribute__((address_space(3))) void*)l, 16, 0, 0);
}

// ---------------------------------------------------------------------------
// K1: fused [chunked LDS histogram] + [W1/W2 transpose -> fp16] + [wl2/wr2]
//     + [h -> fp16]   (R3 form, unchanged)
// ---------------------------------------------------------------------------
constexpr int NCHUNK = 64;
constexpr int EPC    = N_EDGES / NCHUNK;                 // 5000 exactly
constexpr int NB_T1    = 64;                             // W1: 8x8 tiles of 64x64
constexpr int NB_T2    = 8;                              // W2: 8x1 tiles
constexpr int NB_WLR2  = 2;                              // 512 threads
constexpr int NB_PRE   = NCHUNK + NB_T1 + NB_T2 + NB_WLR2;
constexpr int NB_SPLIT = (N_NODES * 512 / 4) / 256;      // 5000 (1 float4/thread)

__global__ __launch_bounds__(256) void prep1_kernel(
                             const float4* __restrict__ h4,
                             ushort* __restrict__ xh,
                             const int* __restrict__ dst, int* __restrict__ ccnt,
                             int* __restrict__ rank,
                             const float* __restrict__ W1, ushort* __restrict__ w1t,
                             const float* __restrict__ W2, ushort* __restrict__ w2t,
                             const float* __restrict__ al2, const float* __restrict__ ar2,
                             float* __restrict__ wl2, float* __restrict__ wr2) {
    // one 40 KB buffer, aliased by hist (int[10000]) and transpose (float, pitch 65)
    __shared__ __align__(16) int shbuf[N_NODES];
    const int b = blockIdx.x;
    if (b < NCHUNK) {
        // ---- chunk histogram ----
        for (int i = threadIdx.x; i < N_NODES; i += 256) shbuf[i] = 0;
        __syncthreads();
        const int e0 = b * EPC;
#pragma unroll 4
        for (int i = threadIdx.x; i < EPC; i += 256) {
            const int e = e0 + i;
            rank[e] = atomicAdd(&shbuf[dst[e]], 1);   // LDS atomic
        }
        __syncthreads();
        for (int i = threadIdx.x; i < N_NODES; i += 256)
            ccnt[b * N_NODES + i] = shbuf[i];         // coalesced
    } else if (b < NCHUNK + NB_T1 + NB_T2) {
        float* smem = (float*)shbuf;                   // [64][65] pitch-65
        const int t0 = b - NCHUNK;
        const bool isW1 = t0 < NB_T1;
        const float* W = isW1 ? W1 : W2;
        ushort* wt = isW1 ? w1t : w2t;
        const int N  = isW1 ? 512 : 64;
        const int t  = isW1 ? t0 : (t0 - NB_T1);
        const int ti = isW1 ? (t & 7) : t;    // K-tile
        const int tj = isW1 ? (t >> 3) : 0;   // N-tile
        const int c  = threadIdx.x & 63;
        const int r0 = threadIdx.x >> 6;      // 0..3
#pragma unroll
        for (int p = 0; p < 16; p++) {
            const int r = p * 4 + r0;
            smem[r * 65 + c] = W[(size_t)(ti * 64 + r) * N + tj * 64 + c];
        }
        __syncthreads();
#pragma unroll
        for (int p = 0; p < 16; p++) {
            const int rr = p * 4 + r0;
            wt[(size_t)(tj * 64 + rr) * 512 + ti * 64 + c] = f2h(smem[c * 65 + rr]);
        }
    } else if (b < NB_PRE) {
        const int k = (b - NCHUNK - NB_T1 - NB_T2) * 256 + threadIdx.x;  // [0,512)
        float sl = 0.f, sr = 0.f;
#pragma unroll 8
        for (int d = 0; d < 64; d++) {
            const float w = W2[(size_t)k * 64 + d];
            sl += w * al2[d];
            sr += w * ar2[d];
        }
        wl2[k] = sl;
        wr2[k] = sr;
    } else {
        const int i = (b - NB_PRE) * 256 + threadIdx.x;
        const float4 v = h4[i];
        *(ushort4*)&xh[i * 4] = make_ushort4(f2h(v.x), f2h(v.y), f2h(v.z), f2h(v.w));
    }
}

// ---------------------------------------------------------------------------
// K2a: per-node exclusive scan across the 64 chunk counts (R3 form).
// ---------------------------------------------------------------------------
__global__ __launch_bounds__(256) void chunkscan_kernel(int* __restrict__ ccnt,
                                                        int* __restrict__ counts) {
    const int n = blockIdx.x * 256 + threadIdx.x;
    if (n >= N_NODES) return;
    int v[NCHUNK];
#pragma unroll
    for (int c = 0; c < NCHUNK; c++) v[c] = ccnt[c * N_NODES + n];
    int run = 0;
#pragma unroll
    for (int c = 0; c < NCHUNK; c++) {
        const int t = v[c];
        ccnt[c * N_NODES + n] = run;
        run += t;
    }
    counts[n] = run;
}

// ---------------------------------------------------------------------------
// K2b: scan counts -> offs. Single 256-thread block (R3 form).
// ---------------------------------------------------------------------------
__global__ void prep2_scan_kernel(const int* __restrict__ counts, int* __restrict__ offs) {
    __shared__ int wsum[4];
    const int tid = threadIdx.x;
    const int lane = tid & 63, wave = tid >> 6;
    const int base = tid * 40;
    int v[40];
    int s = 0;
#pragma unroll
    for (int i = 0; i < 40; i++) {
        v[i] = (base + i < N_NODES) ? counts[base + i] : 0;
        s += v[i];
    }
    int ps = s;
#pragma unroll
    for (int o = 1; o < 64; o <<= 1) {
        const int t = __shfl_up(ps, o);
        if (lane >= o) ps += t;
    }
    if (lane == 63) wsum[wave] = ps;
    __syncthreads();
    if (tid < 4) {
        int t = wsum[tid];
#pragma unroll
        for (int o = 1; o < 4; o <<= 1) {
            const int u = __shfl_up(t, o);
            if (tid >= o) t += u;
        }
        wsum[tid] = t;
    }
    __syncthreads();
    const int wbase = (wave > 0) ? wsum[wave - 1] : 0;
    int run = wbase + ps - s;
#pragma unroll
    for (int i = 0; i < 40; i++) {
        if (base + i < N_NODES) offs[base + i + 1] = run + v[i];
        run += v[i];
    }
    if (tid == 0) offs[0] = 0;
}

// ---------------------------------------------------------------------------
// K3: fused [GEMM1 + el/er epilogue] + [scatter]  (R3 form).
// ---------------------------------------------------------------------------
constexpr int NB_GEMM1 = ((N_NODES + 63) / 64) * 4;      // 628
constexpr int NB_SCAT  = (N_EDGES + 255) / 256;          // 1250

__global__ __launch_bounds__(256) void gemm1_scatter_kernel(
    const ushort* __restrict__ A, const ushort* __restrict__ B,
    ushort* __restrict__ Cout, int M,
    const float* __restrict__ attn_l, const float* __restrict__ attn_r,
    float* __restrict__ elp, float* __restrict__ erp,
    const int* __restrict__ src, const int* __restrict__ dst,
    const int* __restrict__ rank, const int* __restrict__ offs,
    const int* __restrict__ ccnt, int* __restrict__ srcs) {
    constexpr int BM = 64, BN = 128, BK = 64, K = 512, N = 512;

    if ((int)blockIdx.x >= NB_GEMM1) {
        const int i = ((int)blockIdx.x - NB_GEMM1) * 256 + threadIdx.x;
        if (i < N_EDGES) {
            const int c = i / EPC;                     // magic-div (constexpr)
            const int d = dst[i];
            srcs[offs[d] + ccnt[c * N_NODES + d] + rank[i]] = src[i];
        }
        return;
    }

    __shared__ __align__(16) ushort sA[2][BM * BK];   // 8 KB x2
    __shared__ __align__(16) ushort sB[2][BN * BK];   // 16 KB x2

    const int tid = threadIdx.x;
    const int wave = tid >> 6, lane = tid & 63;
    const int m0 = ((int)blockIdx.x >> 2) * BM, n0 = ((int)blockIdx.x & 3) * BN;
    const int wm = wave >> 1, wn = wave & 1;
    const int l31 = lane & 31, lh = lane >> 5;

    // --- staging maps: phys (row, slot) <- global (row, slot ^ (row&7)) ---
    size_t abyte[2]; int afb[2];
#pragma unroll
    for (int p = 0; p < 2; p++) {
        const int fb = tid * 16 + p * 4096;            // [0,8192)
        const int r = fb >> 7, s = (fb >> 4) & 7;
        int ar = m0 + r; if (ar > M - 1) ar = M - 1;
        abyte[p] = (size_t)ar * (K * 2) + (size_t)((s ^ (r & 7)) << 4);
        afb[p] = fb;
    }
    size_t bbyte[4]; int bfb[4];
#pragma unroll
    for (int p = 0; p < 4; p++) {
        const int fb = tid * 16 + p * 4096;            // [0,16384)
        const int r = fb >> 7, s = (fb >> 4) & 7;
        bbyte[p] = (size_t)(n0 + r) * (K * 2) + (size_t)((s ^ (r & 7)) << 4);
        bfb[p] = fb;
    }

    f32x16 acc[2] = {};

    const int rA = wm * 32 + l31;
    const u32 aoff = rA * 128, axr = rA & 7;
    u32 boff[2], bxr[2];
#pragma unroll
    for (int ni = 0; ni < 2; ni++) {
        const int rB = wn * 64 + ni * 32 + l31;
        boff[ni] = rB * 128; bxr[ni] = rB & 7;
    }

    // prologue: stage tile 0
#pragma unroll
    for (int p = 0; p < 2; p++) gload16((const char*)A + abyte[p], (char*)&sA[0][0] + afb[p]);
#pragma unroll
    for (int p = 0; p < 4; p++) gload16((const char*)B + bbyte[p], (char*)&sB[0][0] + bfb[p]);
    __syncthreads();

    int cur = 0;
    for (int k0 = 0; k0 < K; k0 += BK) {
        if (k0 + BK < K) {   // stage next tile while computing current
            const size_t kb = (size_t)(k0 + BK) * 2;
#pragma unroll
            for (int p = 0; p < 2; p++)
                gload16((const char*)A + abyte[p] + kb, (char*)&sA[cur ^ 1][0] + afb[p]);
#pragma unroll
            for (int p = 0; p < 4; p++)
                gload16((const char*)B + bbyte[p] + kb, (char*)&sB[cur ^ 1][0] + bfb[p]);
        }
        const char* pA = (const char*)&sA[cur][0];
        const char* pB = (const char*)&sB[cur][0];
#pragma unroll
        for (int ks = 0; ks < 4; ks++) {
            const u32 sl = ks * 2 + lh;
            const half8 ah = *(const half8*)(pA + aoff + ((sl ^ axr) << 4));
#pragma unroll
            for (int ni = 0; ni < 2; ni++) {
                const half8 bh = *(const half8*)(pB + boff[ni] + ((sl ^ bxr[ni]) << 4));
                acc[ni] = __builtin_amdgcn_mfma_f32_32x32x16_f16(ah, bh, acc[ni], 0, 0, 0);
            }
        }
        __syncthreads();   // drains prefetch vmcnt + protects buffer swap
        cur ^= 1;
    }

    // C layout (m74/m101, dtype-independent): col=lane&31,
    // row=(reg&3)+8*(reg>>2)+4*(lane>>5)
#pragma unroll
    for (int reg = 0; reg < 16; reg++) {
        const int grow = m0 + wm * 32 + (reg & 3) + 8 * (reg >> 2) + 4 * lh;
        if (grow < M) {
#pragma unroll
            for (int ni = 0; ni < 2; ni++) {
                const int gcol = n0 + wn * 64 + ni * 32 + l31;
                Cout[(size_t)grow * N + gcol] = f2h(acc[ni][reg]);
            }
        }
    }

    const int head = (n0 + wn * 64) >> 6;
    float alv[2], arv[2];
#pragma unroll
    for (int ni = 0; ni < 2; ni++) {
        alv[ni] = attn_l[head * 64 + ni * 32 + l31];
        arv[ni] = attn_r[head * 64 + ni * 32 + l31];
    }
#pragma unroll
    for (int reg = 0; reg < 16; reg++) {
        float pl = acc[0][reg] * alv[0] + acc[1][reg] * alv[1];
        float pr = acc[0][reg] * arv[0] + acc[1][reg] * arv[1];
#pragma unroll
        for (int o = 1; o < 32; o <<= 1) {
            pl += __shfl_xor(pl, o);
            pr += __shfl_xor(pr, o);
        }
        const int grow = m0 + wm * 32 + (reg & 3) + 8 * (reg >> 2) + 4 * lh;
        if (l31 == 0 && grow < M) {
            elp[grow * 8 + head] = pl;
            erp[grow * 8 + head] = pr;
        }
    }
}

// ---------------------------------------------------------------------------
// K5: layer-1 aggregation — R9 structure (best measured: 44.7 us, FETCH
// 15 MB L2-resident via XCD-affine pair-slicing, 2 independent edge-chains
// per window) + tail-split: the min-clamp and weight cndmask provably
// do nothing when j+8 <= has, so full windows drop them (bitwise-identical
// accumulation). R10's 8-group reshape regressed (longer serial chain);
// this keeps the proven 4-group x 16-lane shape.
// ---------------------------------------------------------------------------
__global__ __launch_bounds__(256) void agg1_kernel(
    const ushort* __restrict__ feat, const float* __restrict__ el,
    const float* __restrict__ er, const int* __restrict__ offs,
    const int* __restrict__ srcs, ushort* __restrict__ xh,
    const float* __restrict__ wl2, const float* __restrict__ wr2,
    float* __restrict__ plp, float* __restrict__ prp) {
    const int tid = threadIdx.x;
    const int wave = tid >> 6, lane = tid & 63;
    const int pair = blockIdx.x & 3;                  // XCD-affine slice id
    const int node = (blockIdx.x >> 2) * 4 + wave;
    const int start = offs[node];
    const int deg = offs[node + 1] - start;
    const int grp = lane >> 4;                        // edge group 0..3
    const int lig = lane & 15;                        // lane in group
    const int d0  = pair * 128 + lig * 8;             // my 8 dims
    const int myh = pair * 2 + (lig >> 3);            // my head

    if (deg == 0) {
        if (lane < 16) {
            const ushort4 z = make_ushort4(0, 0, 0, 0);
            *(ushort4*)&xh[(size_t)node * 512 + d0]     = z;
            *(ushort4*)&xh[(size_t)node * 512 + d0 + 4] = z;
        }
        if (lane == 0) { plp[node * 4 + pair] = 0.f; prp[node * 4 + pair] = 0.f; }
        return;
    }

    const float er_my = er[node * 8 + myh];

    float acc[8];
#pragma unroll
    for (int i = 0; i < 8; i++) acc[i] = 0.f;
    float ws = 0.f;

    for (int base = 0; base < deg; base += 64) {
        const int has = min(64, deg - base);
        const int s = srcs[start + base + min(lane, has - 1)];
        int j = 0;
        // full 8-edge windows: e0 = j+grp <= j+3 < has and e1 = j+4+grp <=
        // j+7 < has always -> clamps/masks are no-ops, dropped.
        for (; j + 8 <= has; j += 8) {
            const int s0 = __shfl(s, j + grp);
            const int s1 = __shfl(s, j + 4 + grp);
            const float l0 = el[s0 * 8 + myh];
            const float l1 = el[s1 * 8 + myh];
            const half8 u0 = *(const half8*)&feat[(size_t)s0 * 512 + d0];
            const half8 u1 = *(const half8*)&feat[(size_t)s1 * 512 + d0];
            const float w0 = __expf(lrelu(l0 + er_my));
            const float w1 = __expf(lrelu(l1 + er_my));
#pragma unroll
            for (int i = 0; i < 8; i++) acc[i] += w0 * (float)u0[i];
            ws += w0;
#pragma unroll
            for (int i = 0; i < 8; i++) acc[i] += w1 * (float)u1[i];
            ws += w1;
        }
        // tail window (1..7 edges): clamped + masked (original R9 path)
        if (j < has) {
            const int e0 = j + grp, e1 = j + 4 + grp;
            const int s0 = __shfl(s, min(e0, has - 1));
            const int s1 = __shfl(s, min(e1, has - 1));
            const float l0 = el[s0 * 8 + myh];
            const float l1 = el[s1 * 8 + myh];
            const half8 u0 = *(const half8*)&feat[(size_t)s0 * 512 + d0];
            const half8 u1 = *(const half8*)&feat[(size_t)s1 * 512 + d0];
            const float w0 = (e0 < has) ? __expf(lrelu(l0 + er_my)) : 0.f;
            const float w1 = (e1 < has) ? __expf(lrelu(l1 + er_my)) : 0.f;
#pragma unroll
            for (int i = 0; i < 8; i++) acc[i] += w0 * (float)u0[i];
            ws += w0;
#pragma unroll
            for (int i = 0; i < 8; i++) acc[i] += w1 * (float)u1[i];
            ws += w1;
        }
    }

    // combine the 4 edge-groups (same dims live at lanes l, l^16, l^32, l^48)
#pragma unroll
    for (int i = 0; i < 8; i++) {
        acc[i] += __shfl_xor(acc[i], 16);
        acc[i] += __shfl_xor(acc[i], 32);
    }
    ws += __shfl_xor(ws, 16);
    ws += __shfl_xor(ws, 32);

    const float inv = 1.f / ws;
    float o[8];
#pragma unroll
    for (int i = 0; i < 8; i++) o[i] = elu(acc[i] * inv);

    if (lane < 16) {
        ushort hh[8];
#pragma unroll
        for (int i = 0; i < 8; i++) hh[i] = f2h(o[i]);
        *(ushort4*)&xh[(size_t)node * 512 + d0]     = make_ushort4(hh[0], hh[1], hh[2], hh[3]);
        *(ushort4*)&xh[(size_t)node * 512 + d0 + 4] = make_ushort4(hh[4], hh[5], hh[6], hh[7]);
    }

    // per-pair partial layer-2 logits (reduce across the 16 dim-lanes)
    float pl = 0.f, pr = 0.f;
#pragma unroll
    for (int i = 0; i < 8; i++) {
        pl += o[i] * wl2[d0 + i];
        pr += o[i] * wr2[d0 + i];
    }
#pragma unroll
    for (int off = 8; off > 0; off >>= 1) {
        pl += __shfl_xor(pl, off);
        pr += __shfl_xor(pr, off);
    }
    if (lane == 0) { plp[node * 4 + pair] = pl; prp[node * 4 + pair] = pr; }
}

// ---------------------------------------------------------------------------
// GEMM2 (layer 2) + appended partial-logit sum blocks (el2/er2 = sum of the
// 4 pair partials; runs after agg1, before agg2).  (R9 form, unchanged)
// ---------------------------------------------------------------------------
constexpr int NB_G2  = (N_NODES + 31) / 32;              // 313
constexpr int NB_SUM = (N_NODES + 255) / 256;            // 40

__global__ __launch_bounds__(256) void gemm2_kernel(
    const ushort* __restrict__ A, const ushort* __restrict__ B,
    ushort* __restrict__ Cout, int M,
    const float* __restrict__ plp, const float* __restrict__ prp,
    float* __restrict__ el2, float* __restrict__ er2) {
    constexpr int BM = 32, BN = 64, BK = 64, K = 512, N = 64;

    if ((int)blockIdx.x >= NB_G2) {
        const int n = ((int)blockIdx.x - NB_G2) * 256 + threadIdx.x;
        if (n < N_NODES) {
            el2[n] = plp[n * 4] + plp[n * 4 + 1] + plp[n * 4 + 2] + plp[n * 4 + 3];
            er2[n] = prp[n * 4] + prp[n * 4 + 1] + prp[n * 4 + 2] + prp[n * 4 + 3];
        }
        return;
    }

    __shared__ __align__(16) ushort sA[2][BM * BK];   // 4 KB x2
    __shared__ __align__(16) ushort sB[2][BN * BK];   // 8 KB x2

    const int tid = threadIdx.x;
    const int wave = tid >> 6, lane = tid & 63;
    const int m0 = blockIdx.x * BM;
    const int wm = wave >> 1, wn = wave & 1;
    const int quad = lane >> 4, l15 = lane & 15;

    const int fa = tid * 16;                           // [0,4096)
    const int ra = fa >> 7, sa_ = (fa >> 4) & 7;
    int arow = m0 + ra; if (arow > M - 1) arow = M - 1;
    const size_t abyte = (size_t)arow * (K * 2) + (size_t)((sa_ ^ (ra & 7)) << 4);

    size_t bbyte[2]; int bfb[2];
#pragma unroll
    for (int p = 0; p < 2; p++) {
        const int fb = tid * 16 + p * 4096;            // [0,8192)
        const int r = fb >> 7, s = (fb >> 4) & 7;
        bbyte[p] = (size_t)r * (K * 2) + (size_t)((s ^ (r & 7)) << 4);
        bfb[p] = fb;
    }

    f32x4 acc[2] = {};
    const int rA = wm * 16 + l15;
    const u32 aoff = rA * 128, axr = rA & 7;
    u32 boff[2], bxr[2];
#pragma unroll
    for (int ni = 0; ni < 2; ni++) {
        const int rB = wn * 32 + ni * 16 + l15;
        boff[ni] = rB * 128; bxr[ni] = rB & 7;
    }

    gload16((const char*)A + abyte, (char*)&sA[0][0] + fa);
#pragma unroll
    for (int p = 0; p < 2; p++) gload16((const char*)B + bbyte[p], (char*)&sB[0][0] + bfb[p]);
    __syncthreads();

    int cur = 0;
    for (int k0 = 0; k0 < K; k0 += BK) {
        if (k0 + BK < K) {
            const size_t kb = (size_t)(k0 + BK) * 2;
            gload16((const char*)A + abyte + kb, (char*)&sA[cur ^ 1][0] + fa);
#pragma unroll
            for (int p = 0; p < 2; p++)
                gload16((const char*)B + bbyte[p] + kb, (char*)&sB[cur ^ 1][0] + bfb[p]);
        }
        const char* pA = (const char*)&sA[cur][0];
        const char* pB = (const char*)&sB[cur][0];
#pragma unroll
        for (int ks = 0; ks < 2; ks++) {
            const u32 sl = ks * 4 + quad;
            const half8 ah = *(const half8*)(pA + aoff + ((sl ^ axr) << 4));
#pragma unroll
            for (int ni = 0; ni < 2; ni++) {
                const half8 bh = *(const half8*)(pB + boff[ni] + ((sl ^ bxr[ni]) << 4));
                acc[ni] = __builtin_amdgcn_mfma_f32_16x16x32_f16(ah, bh, acc[ni], 0, 0, 0);
            }
        }
        __syncthreads();
        cur ^= 1;
    }

    // C layout 16x16 (m89): col=lane&15, row=(lane>>4)*4+reg
#pragma unroll
    for (int r = 0; r < 4; r++) {
        const int grow = m0 + wm * 16 + quad * 4 + r;
        if (grow < M) {
#pragma unroll
            for (int ni = 0; ni < 2; ni++) {
                const int gcol = wn * 32 + ni * 16 + l15;
                Cout[(size_t)grow * N + gcol] = f2h(acc[ni][r]);
            }
        }
    }
}

// ---------------------------------------------------------------------------
// Layer-2 aggregation (unchanged).
// ---------------------------------------------------------------------------
__global__ __launch_bounds__(256) void agg2_kernel(
    const ushort* __restrict__ feat, const float* __restrict__ el,
    const float* __restrict__ er, const int* __restrict__ offs,
    const int* __restrict__ srcs, float* __restrict__ out) {
    const int tid = threadIdx.x;
    const int wave = tid >> 6, lane = tid & 63;
    const int node = blockIdx.x * 4 + wave;
    const int start = offs[node];
    const int deg = offs[node + 1] - start;
    if (deg == 0) { out[(size_t)node * 64 + lane] = 0.f; return; }
    const float ern = er[node];

    float acc = 0.f, ws = 0.f;
    for (int base = 0; base < deg; base += 64) {
        const int has = min(64, deg - base);
        const int s = srcs[start + base + min(lane, has - 1)];
        const float w = __expf(lrelu(el[s] + ern));
        int j = 0;
        for (; j + 8 <= has; j += 8) {
            float aq[8]; int sq[8];
#pragma unroll
            for (int q = 0; q < 8; q++) { aq[q] = __shfl(w, j + q); sq[q] = __shfl(s, j + q); }
            ushort fq[8];
#pragma unroll
            for (int q = 0; q < 8; q++) fq[q] = feat[(size_t)sq[q] * 64 + lane];
#pragma unroll
            for (int q = 0; q < 8; q++) { acc += aq[q] * h2f(fq[q]); ws += aq[q]; }
        }
        for (; j < has; j++) {
            const float a = __shfl(w, j);
            const int sj = __shfl(s, j);
            acc += a * h2f(feat[(size_t)sj * 64 + lane]);
            ws += a;
        }
    }
    out[(size_t)node * 64 + lane] = acc / ws;
}

// ---------------------------------------------------------------------------
extern "C" void kernel_launch(void* const* d_in, const int* in_sizes, int n_in,
                              void* d_out, int out_size, void* d_ws, size_t ws_size,
                              hipStream_t stream) {
    const float* h   = (const float*)d_in[0];
    const int*   src = (const int*)d_in[1];
    const int*   dst = (const int*)d_in[2];
    const float* W1  = (const float*)d_in[3];
    const float* al1 = (const float*)d_in[4];
    const float* ar1 = (const float*)d_in[5];
    const float* W2  = (const float*)d_in[6];
    const float* al2 = (const float*)d_in[7];
    const float* ar2 = (const float*)d_in[8];
    float* out = (float*)d_out;

    // workspace carve (16B-aligned chunks)
    char* p = (char*)d_ws;
    ushort* feat1 = (ushort*)p; p += (size_t)N_NODES * 512 * 2;   // fp16, 10.24 MB
    ushort* feat2 = (ushort*)p; p += (size_t)N_NODES * 64 * 2;    // fp16
    float* el1   = (float*)p;  p += (size_t)N_NODES * 8 * 4;
    float* er1   = (float*)p;  p += (size_t)N_NODES * 8 * 4;
    float* el2   = (float*)p;  p += (size_t)N_NODES * 4;
    float* er2   = (float*)p;  p += (size_t)N_NODES * 4;
    ushort* xh   = (ushort*)p; p += (size_t)N_NODES * 512 * 2;    // h fp16 -> x1 fp16
    ushort* w1t  = (ushort*)p; p += (size_t)512 * 512 * 2;        // fp16
    ushort* w2t  = (ushort*)p; p += (size_t)64 * 512 * 2;         // fp16
    float* wl2   = (float*)p;  p += (size_t)512 * 4;
    float* wr2   = (float*)p;  p += (size_t)512 * 4;
    int* counts  = (int*)p;    p += (size_t)N_NODES * 4;          // node totals
    int* ccnt    = (int*)p;    p += (size_t)NCHUNK * N_NODES * 4; // 2.56 MB
    int* offs    = (int*)p;    p += (size_t)10004 * 4;
    int* rank    = (int*)p;    p += (size_t)N_EDGES * 4;
    int* srcs    = (int*)p;    p += (size_t)N_EDGES * 4;
    float* plp   = (float*)p;  p += (size_t)N_NODES * 4 * 4;      // pair partials
    float* prp   = (float*)p;  p += (size_t)N_NODES * 4 * 4;

    // 1: fused LDS-hist + W-transposes + wl2/wr2 + h->fp16  (no memset needed)
    prep1_kernel<<<NB_PRE + NB_SPLIT, 256, 0, stream>>>(
        (const float4*)h, xh, dst, ccnt, rank,
        W1, w1t, W2, w2t, al2, ar2, wl2, wr2);

    // 2a: per-node scan over chunks
    chunkscan_kernel<<<(N_NODES + 255) / 256, 256, 0, stream>>>(ccnt, counts);

    // 2b: scan counts -> offs (1 block)
    prep2_scan_kernel<<<1, 256, 0, stream>>>(counts, offs);

    // 3: fused GEMM1 (fp16, dbuf+swizzle, + el/er) + scatter
    gemm1_scatter_kernel<<<NB_GEMM1 + NB_SCAT, 256, 0, stream>>>(
        xh, w1t, feat1, N_NODES, al1, ar1, el1, er1,
        src, dst, rank, offs, ccnt, srcs);

    // 4: layer-1 aggregation (pair-sliced XCD-affine, 16B/lane, tail-split)
    agg1_kernel<<<N_NODES, 256, 0, stream>>>(
        feat1, el1, er1, offs, srcs, xh, wl2, wr2, plp, prp);

    // 5: layer-2 GEMM + partial-logit sum -> el2/er2
    gemm2_kernel<<<NB_G2 + NB_SUM, 256, 0, stream>>>(
        xh, w2t, feat2, N_NODES, plp, prp, el2, er2);

    // 6: layer-2 aggregation -> out
    agg2_kernel<<<N_NODES / 4, 256, 0, stream>>>(feat2, el2, er2, offs, srcs, out);
}